// Round 6
// baseline (328.594 us; speedup 1.0000x reference)
//
#include <hip/hip_runtime.h>
#include <hip/hip_bf16.h>

typedef __bf16 bf16_t;
typedef __bf16 bf16x8 __attribute__((ext_vector_type(8)));
typedef float  f32x4  __attribute__((ext_vector_type(4)));

#define BS 512
#define LH 100
#define NC 64
#define DD 256
#define IC 256
#define KK 32

// workspace layout (bytes):
//  [6,553,600, +393,216)   W bf16 planes
//  [6,946,816, +49,152)    C bf16 planes
//  (S region no longer used: S stays in LDS inside k_mega)
#define OFF_WPL 6553600
#define OFF_CPL (6553600 + 3 * 131072)

// split fp32 into 3 bf16 terms: v == h + l + l2 exactly
__device__ __forceinline__ void split3(float v, bf16_t& h, bf16_t& l, bf16_t& l2) {
    h = (bf16_t)v;  float r1 = v - (float)h;
    l = (bf16_t)r1; float r2 = r1 - (float)l;
    l2 = (bf16_t)r2;
}

__device__ __forceinline__ void split3x8(const float* v, bf16x8& h, bf16x8& l, bf16x8& l2) {
#pragma unroll
    for (int j = 0; j < 8; j++) {
        bf16_t a, b, c;
        split3(v[j], a, b, c);
        h[j] = a; l[j] = b; l2[j] = c;
    }
}

// fp32-faithful 16x16x32 MFMA: 6 kept terms, single correction chain
__device__ __forceinline__ void mfma6(const bf16x8& ah, const bf16x8& al, const bf16x8& al2,
                                      const bf16x8& bh, const bf16x8& bl, const bf16x8& bl2,
                                      f32x4& accM, f32x4& accC) {
    accM = __builtin_amdgcn_mfma_f32_16x16x32_bf16(ah,  bh,  accM, 0, 0, 0);
    accC = __builtin_amdgcn_mfma_f32_16x16x32_bf16(ah,  bl,  accC, 0, 0, 0);
    accC = __builtin_amdgcn_mfma_f32_16x16x32_bf16(al,  bh,  accC, 0, 0, 0);
    accC = __builtin_amdgcn_mfma_f32_16x16x32_bf16(ah,  bl2, accC, 0, 0, 0);
    accC = __builtin_amdgcn_mfma_f32_16x16x32_bf16(al,  bl,  accC, 0, 0, 0);
    accC = __builtin_amdgcn_mfma_f32_16x16x32_bf16(al2, bh,  accC, 0, 0, 0);
}

// stage-1 variant: correction split into TWO interleaved chains (40-deep -> 24/16
// across 8 ks). Reorders only the tiny correction sums (~1e-10 of |S|).
__device__ __forceinline__ void mfma6s(const bf16x8& ah, const bf16x8& al, const bf16x8& al2,
                                       const bf16x8& bh, const bf16x8& bl, const bf16x8& bl2,
                                       f32x4& accM, f32x4& accC0, f32x4& accC1) {
    accM  = __builtin_amdgcn_mfma_f32_16x16x32_bf16(ah,  bh,  accM,  0, 0, 0);
    accC0 = __builtin_amdgcn_mfma_f32_16x16x32_bf16(ah,  bl,  accC0, 0, 0, 0);
    accC1 = __builtin_amdgcn_mfma_f32_16x16x32_bf16(al,  bh,  accC1, 0, 0, 0);
    accC0 = __builtin_amdgcn_mfma_f32_16x16x32_bf16(ah,  bl2, accC0, 0, 0, 0);
    accC1 = __builtin_amdgcn_mfma_f32_16x16x32_bf16(al,  bl,  accC1, 0, 0, 0);
    accC0 = __builtin_amdgcn_mfma_f32_16x16x32_bf16(al2, bh,  accC0, 0, 0, 0);
}

// ---------------------------------------------------------------------------
// fast fp64 tanh: relative error < ~1e-15 (matches OCML tanh to the f32 ulp).
// KEPT IN F64: the top-k on w is rank-sensitive; P perturbations must stay
// ~1e-15 so w ordering vs the reference cannot flip at near-ties.
// ---------------------------------------------------------------------------
__device__ __forceinline__ float fast_tanh_f32(float xf) {
    const double t  = fabs((double)xf) * 2.0;              // t = 2|x| >= 0
    const double nf = rint(t * 1.4426950408889634);        // n = rint(t/ln2)
    double r = fma(nf, -6.93147180369123816490e-01, t);
    r = fma(nf, -1.90821492927058770002e-10, r);           // r in [-0.3466, 0.3466]
    const double r2 = r * r;
    double p =        2.08767569878680989792e-09;          // 1/12!
    p = fma(p, r,     2.50521083854417187751e-08);
    p = fma(p, r,     2.75573192239858906526e-07);
    p = fma(p, r,     2.75573192239858925110e-06);
    p = fma(p, r,     2.48015873015873015873e-05);
    p = fma(p, r,     1.98412698412698412526e-04);
    p = fma(p, r,     1.38888888888888894069e-03);
    p = fma(p, r,     8.33333333333333321769e-03);
    p = fma(p, r,     4.16666666666666643537e-02);
    p = fma(p, r,     1.66666666666666657415e-01);
    p = fma(p, r,     5.00000000000000000000e-01);
    const double q   = fma(r2, p, r);                      // expm1(r), no cancellation
    const double s   = ldexp(1.0, (int)nf);                // 2^n
    const double em1 = fma(s, q, s - 1.0);                 // e^t - 1
    double ti = em1 / (em1 + 2.0);                         // tanh(|x|)
    if (t > 20.0) ti = 1.0;
    return copysignf((float)ti, xf);
}

// fast fp64 exp for x <= 0 (softmax): same machinery, rel err ~2e-16 vs OCML.
__device__ __forceinline__ double fast_exp_f64(double x) {
    const double nf = rint(x * 1.4426950408889634);
    double r = fma(nf, -6.93147180369123816490e-01, x);
    r = fma(nf, -1.90821492927058770002e-10, r);
    const double r2 = r * r;
    double p =        2.08767569878680989792e-09;
    p = fma(p, r,     2.50521083854417187751e-08);
    p = fma(p, r,     2.75573192239858906526e-07);
    p = fma(p, r,     2.75573192239858925110e-06);
    p = fma(p, r,     2.48015873015873015873e-05);
    p = fma(p, r,     1.98412698412698412526e-04);
    p = fma(p, r,     1.38888888888888894069e-03);
    p = fma(p, r,     8.33333333333333321769e-03);
    p = fma(p, r,     4.16666666666666643537e-02);
    p = fma(p, r,     1.66666666666666657415e-01);
    p = fma(p, r,     5.00000000000000000000e-01);
    const double q = fma(r2, p, r);                        // expm1(r)
    const double s = ldexp(1.0, (int)nf);                  // 2^n
    return fma(s, q, s);                                   // e^x
}

// ---------------------------------------------------------------------------
// KP: pre-split W (65536) and C (8192) fp32 -> 3 bf16 planes each
// ---------------------------------------------------------------------------
__global__ __launch_bounds__(256) void kp_split(const float* __restrict__ W,
                                                const float* __restrict__ C,
                                                bf16_t* __restrict__ Wh, bf16_t* __restrict__ Wl,
                                                bf16_t* __restrict__ Wl2,
                                                bf16_t* __restrict__ Ch, bf16_t* __restrict__ Cl,
                                                bf16_t* __restrict__ Cl2) {
    int idx = blockIdx.x * 256 + threadIdx.x;
    if (idx < 65536) {
        bf16_t h, l, l2;
        split3(W[idx], h, l, l2);
        Wh[idx] = h; Wl[idx] = l; Wl2[idx] = l2;
    } else {
        int i = idx - 65536;
        if (i < 8192) {
            bf16_t h, l, l2;
            split3(C[i], h, l, l2);
            Ch[i] = h; Cl[i] = l; Cl2[i] = l2;
        }
    }
}

// ---------------------------------------------------------------------------
// K_MEGA: one block per b, 448 threads (7 waves), everything fused:
//   [k12] P = tanh(H W^T), S = P C^T  (dbuf W staging, S -> LDS)
//   [A]   softmax over l per k        (scratch-free, custom f64 exp)
//   [B]   I = attn @ H
//   [C]   w = cand @ I^T + parallel variable top-k
//   [D]   user = w_masked @ I -> out
// LDS overlay (64,384 B total; 2 blocks/CU):
//   k12:  wbuf[2][24576] at [0,49152) | pl 7x544f at [49152,64384)
//   post: ls[0,12800) | attn[12800,25600) | red[25600,27712)
//         ht/I_l at [27712,...) | shw[0,8448) (phase C/D)
// ---------------------------------------------------------------------------
#define WCH 24576
__global__ __launch_bounds__(448, 4) void k_mega(const float* __restrict__ H,
                                                 const bf16_t* __restrict__ Wh,
                                                 const bf16_t* __restrict__ Wl,
                                                 const bf16_t* __restrict__ Wl2,
                                                 const bf16_t* __restrict__ Ch,
                                                 const bf16_t* __restrict__ Cl,
                                                 const bf16_t* __restrict__ Cl2,
                                                 const int* __restrict__ ni,
                                                 const int* __restrict__ cc,
                                                 const float* __restrict__ cand,
                                                 float* __restrict__ out) {
    __shared__ __align__(16) char smem[64384];
    char* wbuf0 = smem;
    char* wbuf1 = smem + WCH;
    float* pl_all = (float*)(smem + 2 * WCH);     // 7 * 16*34 floats

    float*  ls     = (float*)smem;                // [0, 12800)
    float*  attn_l = (float*)(smem + 12800);      // [12800, 25600)
    double* red    = (double*)(smem + 25600);     // [25600, 27712)
    float*  ht     = (float*)(smem + 27712);      // [27712, 62528)
    float*  I_l    = (float*)(smem + 27712);      // [27712, 60992) pad-260
    float*  shw    = (float*)smem;                // [0, 8448) phases C/D

    const int tid = threadIdx.x;
    const int wave = tid >> 6;               // 0..6
    const int lane = tid & 63;
    const int r = lane & 15, q = lane >> 4;
    const int b = blockIdx.x;
    const int lrow0 = wave * 16;
    const f32x4 zero = {0.f, 0.f, 0.f, 0.f};

    // ======================= k12 part ======================================
    {
        // per-thread staging-item constants (1536 16B items over 448 thr)
        const bf16_t* it_base[4];
        int it_src[4], it_dst[4];
#pragma unroll
        for (int it = 0; it < 4; it++) {
            const int g = tid + it * 448;
            const int p = (g >> 9) & 3, rem = g & 511, row = rem >> 5, grp = rem & 31;
            it_base[it] = (p == 0) ? Wh : (p == 1) ? Wl : Wl2;
            it_src[it] = row * DD + grp * 8;
            it_dst[it] = (p * 16 + row) * 512 + ((grp * 16) ^ ((row & 7) << 4));
        }
        const bool has4 = (tid < 192);       // 1536 = 3*448 + 192

        // load + split A (H rows) once; clamp the single OOB case
        bf16x8 Ah[8], Al[8], Al2[8];
        {
            long grow = (long)b * LH + lrow0 + r;
            const long maxrow = (long)BS * LH - 1;
            if (grow > maxrow) grow = maxrow;          // only b=511, wave 6
            const float* arow = H + (size_t)grow * DD + q * 8;
#pragma unroll
            for (int ks = 0; ks < 8; ks++) {
                const float* ap = arow + ks * 32;
                float4 u = *(const float4*)ap;
                float4 v = *(const float4*)(ap + 4);
                float av[8] = {u.x, u.y, u.z, u.w, v.x, v.y, v.z, v.w};
                split3x8(av, Ah[ks], Al[ks], Al2[ks]);
            }
        }

        f32x4 saccM[2], saccC[2];
        saccM[0] = zero; saccM[1] = zero; saccC[0] = zero; saccC[1] = zero;

        float* myp = pl_all + wave * 544;
        const int swz = (r & 7) << 4;

        // prologue: stage chunk 0 into wbuf0
        {
            bf16x8 p0 = *(const bf16x8*)(it_base[0] + it_src[0]);
            bf16x8 p1 = *(const bf16x8*)(it_base[1] + it_src[1]);
            bf16x8 p2 = *(const bf16x8*)(it_base[2] + it_src[2]);
            bf16x8 p3;
            if (has4) p3 = *(const bf16x8*)(it_base[3] + it_src[3]);
            *(bf16x8*)(wbuf0 + it_dst[0]) = p0;
            *(bf16x8*)(wbuf0 + it_dst[1]) = p1;
            *(bf16x8*)(wbuf0 + it_dst[2]) = p2;
            if (has4) *(bf16x8*)(wbuf0 + it_dst[3]) = p3;
        }
        __syncthreads();

        for (int c16 = 0; c16 < 16; c16++) {
            const char* cur = (c16 & 1) ? wbuf1 : wbuf0;
            char* nxt = (c16 & 1) ? wbuf0 : wbuf1;
            const bool pfv = (c16 < 15);

            // issue next-chunk global loads (latency hides under compute)
            bf16x8 p0, p1, p2, p3;
            if (pfv) {
                const int co = (c16 + 1) * 16 * DD;
                p0 = *(const bf16x8*)(it_base[0] + co + it_src[0]);
                p1 = *(const bf16x8*)(it_base[1] + co + it_src[1]);
                p2 = *(const bf16x8*)(it_base[2] + co + it_src[2]);
                if (has4) p3 = *(const bf16x8*)(it_base[3] + co + it_src[3]);
            }

            // stage 1: one 16-col P tile, full K (split correction chains)
            f32x4 aM = zero, aC0 = zero, aC1 = zero;
#pragma unroll
            for (int ks = 0; ks < 8; ks++) {
                const int colb = (ks * 64 + q * 16) ^ swz;
                const char* rowp = cur + r * 512 + colb;
                bf16x8 bh  = *(const bf16x8*)(rowp);
                bf16x8 bl  = *(const bf16x8*)(rowp + 8192);
                bf16x8 bl2 = *(const bf16x8*)(rowp + 16384);
                mfma6s(Ah[ks], Al[ks], Al2[ks], bh, bl, bl2, aM, aC0, aC1);
            }

            // tanh -> per-wave pl (wave-local LDS round trip)
            const int colb2 = (c16 & 1) * 16;
#pragma unroll
            for (int i = 0; i < 4; i++) {
                float s1 = aM[i] + aC0[i] + aC1[i];
                myp[(q * 4 + i) * 34 + colb2 + r] = fast_tanh_f32(s1);
            }

            // stage 2 on odd chunks: S += P_pair(32 cols) @ C_pair^T
            if (c16 & 1) {
                const int c0 = (c16 >> 1) * 32;
                const float* ps = myp + r * 34 + q * 8;
                float pv[8];
#pragma unroll
                for (int j = 0; j < 8; j++) pv[j] = ps[j];
                bf16x8 ph, plo, pl2;
                split3x8(pv, ph, plo, pl2);
#pragma unroll
                for (int ntS = 0; ntS < 2; ntS++) {
                    const size_t base = (size_t)(ntS * 16 + r) * IC + c0 + q * 8;
                    bf16x8 ch  = *(const bf16x8*)(Ch  + base);
                    bf16x8 cl  = *(const bf16x8*)(Cl  + base);
                    bf16x8 cl2 = *(const bf16x8*)(Cl2 + base);
                    mfma6(ph, plo, pl2, ch, cl, cl2, saccM[ntS], saccC[ntS]);
                }
            }

            // write prefetched chunk into the other buffer (late)
            if (pfv) {
                *(bf16x8*)(nxt + it_dst[0]) = p0;
                *(bf16x8*)(nxt + it_dst[1]) = p1;
                *(bf16x8*)(nxt + it_dst[2]) = p2;
                if (has4) *(bf16x8*)(nxt + it_dst[3]) = p3;
            }
            __syncthreads();
        }

        // S -> LDS (overlays dead wbuf0); same f32 bits as the old global S
#pragma unroll
        for (int ntS = 0; ntS < 2; ntS++)
#pragma unroll
            for (int i = 0; i < 4; i++) {
                const int lrow = lrow0 + q * 4 + i;
                if (lrow < LH)
                    ls[lrow * KK + ntS * 16 + r] = saccM[ntS][i] + saccC[ntS][i];
            }
    }
    __syncthreads();

    // ======================= phase A: softmax ==============================
    {
        const int k = tid & 31;
        const int grp = tid >> 5;                // only grp<8 active
        const bool act = (grp < 8);
        const int nib = ni[b];

        double vals[13];                         // STATIC indexing -> registers
        if (act) {
            double vmax = -1e300;
#pragma unroll
            for (int i = 0; i < 13; i++) {
                const int l = grp + 8 * i;
                double v = (l < LH) ? (double)ls[l * KK + k] : -1e300;
                vals[i] = v;
                vmax = fmax(vmax, v);
            }
            red[grp * 33 + k] = vmax;
        }
        __syncthreads();
        if (tid < 32) {
            double m = red[k];
            for (int j = 1; j < 8; j++) m = fmax(m, red[j * 33 + k]);
            red[k] = m;
        }
        __syncthreads();
        const double mx = red[k];
        __syncthreads();

        if (act) {
            double s = 0.0;
#pragma unroll
            for (int i = 0; i < 13; i++) {
                const int l = grp + 8 * i;
                if (l < LH) {
                    double e = fast_exp_f64(vals[i] - mx);
                    vals[i] = e;
                    s += e;
                }
            }
            red[grp * 33 + k] = s;
        }
        __syncthreads();
        if (tid < 32) {
            double t = 0.0;
            for (int j = 0; j < 8; j++) t += red[j * 33 + k];
            red[k] = t;
        }
        __syncthreads();
        const double inv = 1.0 / red[k];

        if (act) {
            float* ab = attn_l + k * LH;
            const bool masked = (k >= nib);
#pragma unroll
            for (int i = 0; i < 13; i++) {
                const int l = grp + 8 * i;
                if (l < LH) ab[l] = masked ? 0.01f : (float)(vals[i] * inv);
            }
        }
    }
    __syncthreads();   // attn complete; ls dead

    // ======================= phase B: I = attn @ H =========================
    // 32 tiles (2m x 16n) over 7 waves; mt fixed per wave (A-split hoist).
    {
        const float* Hb = H + (size_t)b * LH * DD;
        const int mtB = wave & 1;
        const int m0B = mtB * 16;
        const int wg = wave >> 1;                // 0..3 (mt=0), 0..2 (mt=1)
        const int strideB = mtB ? 3 : 4;
        const int njj = mtB ? 6 : 4;

        f32x4 accM[6], accC[6];
#pragma unroll
        for (int jj = 0; jj < 6; jj++) { accM[jj] = zero; accC[jj] = zero; }

        for (int ks = 0; ks < 4; ks++) {
            const int l0c = ks * 32;
            __syncthreads();
            for (int u = tid; u < 32 * 64; u += 448) {
                const int l = u >> 6, dg = u & 63;
                float4 v = {0.f, 0.f, 0.f, 0.f};
                if (l0c + l < LH) v = *(const float4*)(Hb + (size_t)(l0c + l) * DD + dg * 4);
                ht[(dg * 4 + 0) * 34 + l] = v.x;
                ht[(dg * 4 + 1) * 34 + l] = v.y;
                ht[(dg * 4 + 2) * 34 + l] = v.z;
                ht[(dg * 4 + 3) * 34 + l] = v.w;
            }
            __syncthreads();

            float av[8];
#pragma unroll
            for (int j = 0; j < 8; j++) {
                const int l = l0c + q * 8 + j;
                av[j] = (l < LH) ? attn_l[(m0B + r) * LH + l] : 0.f;
            }
            bf16x8 ah, al, al2;
            split3x8(av, ah, al, al2);

#pragma unroll
            for (int jj = 0; jj < 6; jj++) {
                const int nt = wg + strideB * jj;
                if (jj < njj && nt < 16) {
                    const int n0 = nt * 16;
                    float bv[8];
                    const float* hp = ht + (n0 + r) * 34 + q * 8;
#pragma unroll
                    for (int j = 0; j < 8; j++) bv[j] = hp[j];
                    bf16x8 bh, bl, bl2;
                    split3x8(bv, bh, bl, bl2);
                    mfma6(ah, al, al2, bh, bl, bl2, accM[jj], accC[jj]);
                }
            }
        }
        __syncthreads();   // done reading ht; I_l overlays it

#pragma unroll
        for (int jj = 0; jj < 6; jj++) {
            const int nt = wg + strideB * jj;
            if (jj < njj && nt < 16) {
                const int n0 = nt * 16;
#pragma unroll
                for (int i = 0; i < 4; i++)
                    I_l[(m0B + q * 4 + i) * 260 + n0 + r] = accM[jj][i] + accC[jj][i];
            }
        }
    }
    __syncthreads();   // I complete; attn dead

    // ======================= phase C: w GEMM + parallel top-k ==============
    {
        const float* Cb = cand + (size_t)b * NC * DD;
        for (int job = wave; job < 8; job += 7) {     // wave0: jobs 0,7
            const int mt = job >> 1, nt = job & 1;
            const int m0 = mt * 16, n0 = nt * 16;
            f32x4 accM = zero, accC = zero;
#pragma unroll
            for (int ks = 0; ks < 8; ks++) {
                const float* ap = Cb + (size_t)(m0 + r) * DD + ks * 32 + q * 8;
                const float* bp = I_l + (n0 + r) * 260 + ks * 32 + q * 8;
                float4 u1 = *(const float4*)ap;      float4 u2 = *(const float4*)(ap + 4);
                float4 v1 = *(const float4*)bp;      float4 v2 = *(const float4*)(bp + 4);
                float av[8] = {u1.x,u1.y,u1.z,u1.w,u2.x,u2.y,u2.z,u2.w};
                float bv[8] = {v1.x,v1.y,v1.z,v1.w,v2.x,v2.y,v2.z,v2.w};
                bf16x8 ah, al, al2, bh, bl, bl2;
                split3x8(av, ah, al, al2);
                split3x8(bv, bh, bl, bl2);
                mfma6(ah, al, al2, bh, bl, bl2, accM, accC);
            }
#pragma unroll
            for (int i = 0; i < 4; i++) shw[(m0 + q * 4 + i) * 33 + n0 + r] = accM[i] + accC[i];
        }
        __syncthreads();

        // parallel variable top-k: n = tid&63, k-group = tid>>6 (7 groups)
        {
            const int n = tid & 63;
            const int kg = tid >> 6;             // 0..6
            int c8 = 8 * cc[b];
            int dynK = 32 - __clz(c8 - 1);
            dynK = min(max(dynK, 1), KK);
            float v[KK];
#pragma unroll
            for (int j = 0; j < KK; j++) v[j] = shw[n * 33 + j];
            float keep[5];
#pragma unroll
            for (int j = 0; j < 5; j++) {
                const int kk2 = kg + 7 * j;
                if (kk2 < KK) {
                    int rank = 0;
#pragma unroll
                    for (int jj = 0; jj < KK; jj++)
                        rank += (v[jj] > v[kk2]) || (v[jj] == v[kk2] && jj < kk2);
                    keep[j] = (rank < dynK) ? v[kk2] : 0.f;
                }
            }
            __syncthreads();                     // all reads done before writes
#pragma unroll
            for (int j = 0; j < 5; j++) {
                const int kk2 = kg + 7 * j;
                if (kk2 < KK) shw[n * 33 + kk2] = keep[j];
            }
        }
    }
    __syncthreads();   // masked w complete

    // ======================= phase D: user = w_masked @ I ==================
    if (tid < 256) {
        const int d = tid;
        float icol[KK];
#pragma unroll
        for (int kk2 = 0; kk2 < KK; kk2++) icol[kk2] = I_l[kk2 * 260 + d];

        for (int n = 0; n < NC; n++) {
            const float* wr = shw + n * 33;
            float acc = 0.f;
#pragma unroll
            for (int kk2 = 0; kk2 < KK; kk2++) acc += wr[kk2] * icol[kk2];
            out[((size_t)b * NC + n) * DD + d] = acc;
        }
    }
}

// ---------------------------------------------------------------------------
extern "C" void kernel_launch(void* const* d_in, const int* in_sizes, int n_in,
                              void* d_out, int out_size, void* d_ws, size_t ws_size,
                              hipStream_t stream) {
    const float* hist = (const float*)d_in[0];
    const float* cand = (const float*)d_in[2];
    const int* ni = (const int*)d_in[3];
    const int* cc = (const int*)d_in[4];
    const float* W = (const float*)d_in[5];
    const float* C = (const float*)d_in[6];
    float* out = (float*)d_out;

    char* w8 = (char*)d_ws;
    bf16_t* Wh  = (bf16_t*)(w8 + OFF_WPL);
    bf16_t* Wl  = (bf16_t*)(w8 + OFF_WPL + 131072);
    bf16_t* Wl2 = (bf16_t*)(w8 + OFF_WPL + 262144);
    bf16_t* Ch  = (bf16_t*)(w8 + OFF_CPL);
    bf16_t* Cl  = (bf16_t*)(w8 + OFF_CPL + 16384);
    bf16_t* Cl2 = (bf16_t*)(w8 + OFF_CPL + 32768);

    kp_split<<<288, 256, 0, stream>>>(W, C, Wh, Wl, Wl2, Ch, Cl, Cl2);
    k_mega<<<BS, 448, 0, stream>>>(hist, Wh, Wl, Wl2, Ch, Cl, Cl2, ni, cc, cand, out);
}

// Round 8
// 231.981 us; speedup vs baseline: 1.4165x; 1.4165x over previous
//
#include <hip/hip_runtime.h>
#include <hip/hip_bf16.h>

typedef __bf16 bf16_t;
typedef __bf16 bf16x8 __attribute__((ext_vector_type(8)));
typedef float  f32x4  __attribute__((ext_vector_type(4)));

#define BS 512
#define LH 100
#define NC 64
#define DD 256
#define IC 256
#define KK 32

// workspace layout (bytes), peak 23,330,816 (proven-safe):
//  [0, 6,553,600)          S fp32 (k12 out, read by fused kernel)
//  [6,553,600, +393,216)   W bf16 planes
//  [6,946,816, +49,152)    C bf16 planes
#define OFF_WPL 6553600
#define OFF_CPL (6553600 + 3 * 131072)

// split fp32 into 3 bf16 terms: v == h + l + l2 exactly
__device__ __forceinline__ void split3(float v, bf16_t& h, bf16_t& l, bf16_t& l2) {
    h = (bf16_t)v;  float r1 = v - (float)h;
    l = (bf16_t)r1; float r2 = r1 - (float)l;
    l2 = (bf16_t)r2;
}

__device__ __forceinline__ void split3x8(const float* v, bf16x8& h, bf16x8& l, bf16x8& l2) {
#pragma unroll
    for (int j = 0; j < 8; j++) {
        bf16_t a, b, c;
        split3(v[j], a, b, c);
        h[j] = a; l[j] = b; l2[j] = c;
    }
}

// fp32-faithful 16x16x32 MFMA: 6 kept terms, single correction chain
__device__ __forceinline__ void mfma6(const bf16x8& ah, const bf16x8& al, const bf16x8& al2,
                                      const bf16x8& bh, const bf16x8& bl, const bf16x8& bl2,
                                      f32x4& accM, f32x4& accC) {
    accM = __builtin_amdgcn_mfma_f32_16x16x32_bf16(ah,  bh,  accM, 0, 0, 0);
    accC = __builtin_amdgcn_mfma_f32_16x16x32_bf16(ah,  bl,  accC, 0, 0, 0);
    accC = __builtin_amdgcn_mfma_f32_16x16x32_bf16(al,  bh,  accC, 0, 0, 0);
    accC = __builtin_amdgcn_mfma_f32_16x16x32_bf16(ah,  bl2, accC, 0, 0, 0);
    accC = __builtin_amdgcn_mfma_f32_16x16x32_bf16(al,  bl,  accC, 0, 0, 0);
    accC = __builtin_amdgcn_mfma_f32_16x16x32_bf16(al2, bh,  accC, 0, 0, 0);
}

// stage-1 variant: correction split into TWO interleaved chains (validated r6)
__device__ __forceinline__ void mfma6s(const bf16x8& ah, const bf16x8& al, const bf16x8& al2,
                                       const bf16x8& bh, const bf16x8& bl, const bf16x8& bl2,
                                       f32x4& accM, f32x4& accC0, f32x4& accC1) {
    accM  = __builtin_amdgcn_mfma_f32_16x16x32_bf16(ah,  bh,  accM,  0, 0, 0);
    accC0 = __builtin_amdgcn_mfma_f32_16x16x32_bf16(ah,  bl,  accC0, 0, 0, 0);
    accC1 = __builtin_amdgcn_mfma_f32_16x16x32_bf16(al,  bh,  accC1, 0, 0, 0);
    accC0 = __builtin_amdgcn_mfma_f32_16x16x32_bf16(ah,  bl2, accC0, 0, 0, 0);
    accC1 = __builtin_amdgcn_mfma_f32_16x16x32_bf16(al,  bl,  accC1, 0, 0, 0);
    accC0 = __builtin_amdgcn_mfma_f32_16x16x32_bf16(al2, bh,  accC0, 0, 0, 0);
}

// ---------------------------------------------------------------------------
// fast fp64 tanh: relative error < ~1e-15 (matches OCML tanh to the f32 ulp)
// ---------------------------------------------------------------------------
__device__ __forceinline__ float fast_tanh_f32(float xf) {
    const double t  = fabs((double)xf) * 2.0;              // t = 2|x| >= 0
    const double nf = rint(t * 1.4426950408889634);        // n = rint(t/ln2)
    double r = fma(nf, -6.93147180369123816490e-01, t);
    r = fma(nf, -1.90821492927058770002e-10, r);           // r in [-0.3466, 0.3466]
    const double r2 = r * r;
    double p =        2.08767569878680989792e-09;          // 1/12!
    p = fma(p, r,     2.50521083854417187751e-08);
    p = fma(p, r,     2.75573192239858906526e-07);
    p = fma(p, r,     2.75573192239858925110e-06);
    p = fma(p, r,     2.48015873015873015873e-05);
    p = fma(p, r,     1.98412698412698412526e-04);
    p = fma(p, r,     1.38888888888888894069e-03);
    p = fma(p, r,     8.33333333333333321769e-03);
    p = fma(p, r,     4.16666666666666643537e-02);
    p = fma(p, r,     1.66666666666666657415e-01);
    p = fma(p, r,     5.00000000000000000000e-01);
    const double q   = fma(r2, p, r);                      // expm1(r), no cancellation
    const double s   = ldexp(1.0, (int)nf);                // 2^n
    const double em1 = fma(s, q, s - 1.0);                 // e^t - 1
    double ti = em1 / (em1 + 2.0);                         // tanh(|x|)
    if (t > 20.0) ti = 1.0;
    return copysignf((float)ti, xf);
}

// fast fp64 exp (softmax, x<=0): same machinery, rel err ~2e-16 (validated r6)
__device__ __forceinline__ double fast_exp_f64(double x) {
    const double nf = rint(x * 1.4426950408889634);
    double r = fma(nf, -6.93147180369123816490e-01, x);
    r = fma(nf, -1.90821492927058770002e-10, r);
    const double r2 = r * r;
    double p =        2.08767569878680989792e-09;
    p = fma(p, r,     2.50521083854417187751e-08);
    p = fma(p, r,     2.75573192239858906526e-07);
    p = fma(p, r,     2.75573192239858925110e-06);
    p = fma(p, r,     2.48015873015873015873e-05);
    p = fma(p, r,     1.98412698412698412526e-04);
    p = fma(p, r,     1.38888888888888894069e-03);
    p = fma(p, r,     8.33333333333333321769e-03);
    p = fma(p, r,     4.16666666666666643537e-02);
    p = fma(p, r,     1.66666666666666657415e-01);
    p = fma(p, r,     5.00000000000000000000e-01);
    const double q = fma(r2, p, r);                        // expm1(r)
    const double s = ldexp(1.0, (int)nf);                  // 2^n
    return fma(s, q, s);                                   // e^x
}

// ---------------------------------------------------------------------------
// KP: pre-split W (65536) and C (8192) fp32 -> 3 bf16 planes each
// ---------------------------------------------------------------------------
__global__ __launch_bounds__(256) void kp_split(const float* __restrict__ W,
                                                const float* __restrict__ C,
                                                bf16_t* __restrict__ Wh, bf16_t* __restrict__ Wl,
                                                bf16_t* __restrict__ Wl2,
                                                bf16_t* __restrict__ Ch, bf16_t* __restrict__ Cl,
                                                bf16_t* __restrict__ Cl2) {
    int idx = blockIdx.x * 256 + threadIdx.x;
    if (idx < 65536) {
        bf16_t h, l, l2;
        split3(W[idx], h, l, l2);
        Wh[idx] = h; Wl[idx] = l; Wl2[idx] = l2;
    } else {
        int i = idx - 65536;
        if (i < 8192) {
            bf16_t h, l, l2;
            split3(C[i], h, l, l2);
            Ch[i] = h; Cl[i] = l; Cl2[i] = l2;
        }
    }
}

// ---------------------------------------------------------------------------
// K12: P = tanh(H W^T) (fp32-faithful), S = P C^T (fp32-faithful).
// Round-5 form (90us): 448thr/block, one block per b, dbuf async W staging,
// one barrier per chunk, XOR-swizzled LDS. NO launch-bounds min (r6 lesson:
// min-waves=4 capped unified VGPR at 128 -> spill storm, 10x FETCH_SIZE).
// ---------------------------------------------------------------------------
#define WCH 24576   // bytes per W-chunk buffer: 3 planes * 16 rows * 512 B
__global__ __launch_bounds__(448) void k12_proj_scores(const float* __restrict__ H,
                                                       const bf16_t* __restrict__ Wh,
                                                       const bf16_t* __restrict__ Wl,
                                                       const bf16_t* __restrict__ Wl2,
                                                       const bf16_t* __restrict__ Ch,
                                                       const bf16_t* __restrict__ Cl,
                                                       const bf16_t* __restrict__ Cl2,
                                                       float* __restrict__ S) {
    __shared__ __align__(16) char wbuf[2][WCH];   // 49,152 B
    __shared__ float pl[7][16 * 34];              // 15,232 B (per-wave P pair-chunk)

    const int tid = threadIdx.x;
    const int wave = tid >> 6;               // 0..6
    const int lane = tid & 63;
    const int r = lane & 15, q = lane >> 4;
    const int b = blockIdx.x;
    const int lrow0 = wave * 16;             // local row of this wave's tile

    // per-thread staging-item constants (1536 16B items over 448 thr)
    const bf16_t* it_base[4];
    int it_src[4], it_dst[4];
#pragma unroll
    for (int it = 0; it < 4; it++) {
        const int g = tid + it * 448;
        const int p = (g >> 9) & 3, rem = g & 511, row = rem >> 5, grp = rem & 31;
        it_base[it] = (p == 0) ? Wh : (p == 1) ? Wl : Wl2;
        it_src[it] = row * DD + grp * 8;
        it_dst[it] = (p * 16 + row) * 512 + ((grp * 16) ^ ((row & 7) << 4));
    }
    const bool has4 = (tid < 192);           // 1536 = 3*448 + 192

    // load + split A (H rows) once; clamp the single OOB case
    bf16x8 Ah[8], Al[8], Al2[8];
    {
        long grow = (long)b * LH + lrow0 + r;
        const long maxrow = (long)BS * LH - 1;
        if (grow > maxrow) grow = maxrow;              // only b=511, wave 6
        const float* arow = H + (size_t)grow * DD + q * 8;
#pragma unroll
        for (int ks = 0; ks < 8; ks++) {
            const float* ap = arow + ks * 32;
            float4 u = *(const float4*)ap;
            float4 v = *(const float4*)(ap + 4);
            float av[8] = {u.x, u.y, u.z, u.w, v.x, v.y, v.z, v.w};
            split3x8(av, Ah[ks], Al[ks], Al2[ks]);
        }
    }

    const f32x4 zero = {0.f, 0.f, 0.f, 0.f};
    f32x4 saccM[2], saccC[2];
    saccM[0] = zero; saccM[1] = zero; saccC[0] = zero; saccC[1] = zero;

    float* myp = pl[wave];
    const int swz = (r & 7) << 4;

    // prologue: stage chunk 0 into wbuf[0]
    {
        bf16x8 p0 = *(const bf16x8*)(it_base[0] + it_src[0]);
        bf16x8 p1 = *(const bf16x8*)(it_base[1] + it_src[1]);
        bf16x8 p2 = *(const bf16x8*)(it_base[2] + it_src[2]);
        bf16x8 p3;
        if (has4) p3 = *(const bf16x8*)(it_base[3] + it_src[3]);
        *(bf16x8*)(wbuf[0] + it_dst[0]) = p0;
        *(bf16x8*)(wbuf[0] + it_dst[1]) = p1;
        *(bf16x8*)(wbuf[0] + it_dst[2]) = p2;
        if (has4) *(bf16x8*)(wbuf[0] + it_dst[3]) = p3;
    }
    __syncthreads();

    for (int c16 = 0; c16 < 16; c16++) {
        const char* cur = wbuf[c16 & 1];
        char* nxt = wbuf[(c16 & 1) ^ 1];
        const bool pfv = (c16 < 15);

        // issue next-chunk global loads (latency hides under compute)
        bf16x8 p0, p1, p2, p3;
        if (pfv) {
            const int co = (c16 + 1) * 16 * DD;
            p0 = *(const bf16x8*)(it_base[0] + co + it_src[0]);
            p1 = *(const bf16x8*)(it_base[1] + co + it_src[1]);
            p2 = *(const bf16x8*)(it_base[2] + co + it_src[2]);
            if (has4) p3 = *(const bf16x8*)(it_base[3] + co + it_src[3]);
        }

        // stage 1: one 16-col P tile, full K (split correction chains)
        f32x4 aM = zero, aC0 = zero, aC1 = zero;
#pragma unroll
        for (int ks = 0; ks < 8; ks++) {
            const int colb = (ks * 64 + q * 16) ^ swz;
            const char* rowp = cur + r * 512 + colb;
            bf16x8 bh  = *(const bf16x8*)(rowp);
            bf16x8 bl  = *(const bf16x8*)(rowp + 8192);
            bf16x8 bl2 = *(const bf16x8*)(rowp + 16384);
            mfma6s(Ah[ks], Al[ks], Al2[ks], bh, bl, bl2, aM, aC0, aC1);
        }

        // tanh -> per-wave pl (wave-local LDS round trip)
        const int colb2 = (c16 & 1) * 16;
#pragma unroll
        for (int i = 0; i < 4; i++) {
            float s1 = aM[i] + aC0[i] + aC1[i];
            myp[(q * 4 + i) * 34 + colb2 + r] = fast_tanh_f32(s1);
        }

        // stage 2 on odd chunks: S += P_pair(32 cols) @ C_pair^T
        if (c16 & 1) {
            const int c0 = (c16 >> 1) * 32;
            const float* ps = myp + r * 34 + q * 8;
            float pv[8];
#pragma unroll
            for (int j = 0; j < 8; j++) pv[j] = ps[j];
            bf16x8 ph, plo, pl2;
            split3x8(pv, ph, plo, pl2);
#pragma unroll
            for (int ntS = 0; ntS < 2; ntS++) {
                const size_t base = (size_t)(ntS * 16 + r) * IC + c0 + q * 8;
                bf16x8 ch  = *(const bf16x8*)(Ch  + base);
                bf16x8 cl  = *(const bf16x8*)(Cl  + base);
                bf16x8 cl2 = *(const bf16x8*)(Cl2 + base);
                mfma6(ph, plo, pl2, ch, cl, cl2, saccM[ntS], saccC[ntS]);
            }
        }

        // write prefetched chunk into the other buffer (late)
        if (pfv) {
            *(bf16x8*)(nxt + it_dst[0]) = p0;
            *(bf16x8*)(nxt + it_dst[1]) = p1;
            *(bf16x8*)(nxt + it_dst[2]) = p2;
            if (has4) *(bf16x8*)(nxt + it_dst[3]) = p3;
        }
        __syncthreads();   // one barrier per chunk
    }

#pragma unroll
    for (int ntS = 0; ntS < 2; ntS++)
#pragma unroll
        for (int i = 0; i < 4; i++) {
            const int lrow = lrow0 + q * 4 + i;
            if (lrow < LH)
                S[((size_t)b * LH + lrow) * KK + ntS * 16 + r] = saccM[ntS][i] + saccC[ntS][i];
        }
}

// ---------------------------------------------------------------------------
// K3456 fused (512 threads): softmax (A) -> interests GEMM (B) ->
// w GEMM + top-k (C) -> user GEMM (D), intermediates in LDS.
// r7 bug was an LDS-overlay swap: attn_l MUST be at [0,12800) (live through
// phase B) and ls at [12800,25600) (dead after A, overlaid by ht). This is
// the proven r4 overlay, restored:
//   [0,12800)        attn_l [KK][LH] (A,B)  / shw [64][33] (C,D)
//   [12800,25600)    ls (A)
//   [25600,27712)    red (A)
//   [12800,47616)    ht [256][34] (B) / I_l [32][260] (B,C,D)
// Kept from r7 (validated in r6's mega-kernel): static-unroll scratch-free
// softmax, fast_exp_f64, 512-thread parallel top-k.
// ---------------------------------------------------------------------------
__global__ __launch_bounds__(512) void k3456_fused(const float* __restrict__ Sg,
                                                   const int* __restrict__ ni,
                                                   const int* __restrict__ cc,
                                                   const float* __restrict__ H,
                                                   const float* __restrict__ cand,
                                                   float* __restrict__ out) {
    __shared__ __align__(16) char smem[47616];
    float*  attn_l = (float*)smem;               // [0, 12800)      (A,B)
    float*  ls     = (float*)(smem + 12800);     // [12800, 25600)  (A)
    double* red    = (double*)(smem + 25600);    // [25600, 27712)  (A)
    float*  ht     = (float*)(smem + 12800);     // [12800, 47616)  (B)
    float*  I_l    = (float*)(smem + 12800);     // [32][260] pad-4 (B,C,D)
    float*  shw    = (float*)smem;               // [64][33]        (C,D)

    const int b = blockIdx.x;
    const int tid = threadIdx.x;
    const int wave = tid >> 6;                   // 0..7
    const int lane = tid & 63;
    const int r = lane & 15, q = lane >> 4;
    const f32x4 zero = {0.f, 0.f, 0.f, 0.f};

    // ================= phase A: softmax over l per (b,k) (k3) ==============
    {
        const float* Sb = Sg + (size_t)b * LH * KK;
        for (int i = tid; i < LH * KK; i += 512) ls[i] = Sb[i];
        __syncthreads();

        const int k = tid & 31;
        const int grp = tid >> 5;                // 0..15; only grp<8 active
        const bool act = (grp < 8);
        const int nib = ni[b];

        double vals[13];                         // STATIC indexing -> registers
        if (act) {
            double vmax = -1e300;
#pragma unroll
            for (int i = 0; i < 13; i++) {
                const int l = grp + 8 * i;
                double v = (l < LH) ? (double)ls[l * KK + k] : -1e300;
                vals[i] = v;
                vmax = fmax(vmax, v);
            }
            red[grp * 33 + k] = vmax;
        }
        __syncthreads();
        if (tid < 32) {
            double m = red[k];
            for (int j = 1; j < 8; j++) m = fmax(m, red[j * 33 + k]);
            red[k] = m;
        }
        __syncthreads();
        const double mx = red[k];
        __syncthreads();

        if (act) {
            double s = 0.0;
#pragma unroll
            for (int i = 0; i < 13; i++) {
                const int l = grp + 8 * i;
                if (l < LH) {
                    double e = fast_exp_f64(vals[i] - mx);
                    vals[i] = e;
                    s += e;
                }
            }
            red[grp * 33 + k] = s;
        }
        __syncthreads();
        if (tid < 32) {
            double t = 0.0;
            for (int j = 0; j < 8; j++) t += red[j * 33 + k];
            red[k] = t;
        }
        __syncthreads();
        const double inv = 1.0 / red[k];

        if (act) {
            float* ab = attn_l + k * LH;
            const bool masked = (k >= nib);
#pragma unroll
            for (int i = 0; i < 13; i++) {
                const int l = grp + 8 * i;
                if (l < LH) ab[l] = masked ? 0.01f : (float)(vals[i] * inv);
            }
        }
    }
    __syncthreads();   // attn complete; ls/red dead (ht may now overwrite)

    // ================= phase B: I = attn @ H (k4) ==========================
    // 32 tiles (2m x 16n) over 8 waves x 4 jj; mt = wave&1 (A-split hoisted).
    {
        const float* Hb = H + (size_t)b * LH * DD;
        const int mtB = wave & 1;
        const int m0B = mtB * 16;

        f32x4 accM[4], accC[4];
#pragma unroll
        for (int jj = 0; jj < 4; jj++) { accM[jj] = zero; accC[jj] = zero; }

        for (int ks = 0; ks < 4; ks++) {
            const int l0c = ks * 32;
            __syncthreads();
            // stage transposed H chunk: l in [l0c, l0c+32) -> ht[d][l-l0c]
            for (int u = tid; u < 32 * 64; u += 512) {
                const int l = u >> 6, dg = u & 63;
                float4 v = {0.f, 0.f, 0.f, 0.f};
                if (l0c + l < LH) v = *(const float4*)(Hb + (size_t)(l0c + l) * DD + dg * 4);
                ht[(dg * 4 + 0) * 34 + l] = v.x;
                ht[(dg * 4 + 1) * 34 + l] = v.y;
                ht[(dg * 4 + 2) * 34 + l] = v.z;
                ht[(dg * 4 + 3) * 34 + l] = v.w;
            }
            __syncthreads();

            // hoisted A (attn rows) load + split: same values for all jj
            float av[8];
#pragma unroll
            for (int j = 0; j < 8; j++) {
                const int l = l0c + q * 8 + j;
                av[j] = (l < LH) ? attn_l[(m0B + r) * LH + l] : 0.f;
            }
            bf16x8 ah, al, al2;
            split3x8(av, ah, al, al2);

#pragma unroll
            for (int jj = 0; jj < 4; jj++) {
                const int job = wave + jj * 8;
                const int nt = job >> 1;
                const int n0 = nt * 16;
                float bv[8];
                const float* hp = ht + (n0 + r) * 34 + q * 8;
#pragma unroll
                for (int j = 0; j < 8; j++) bv[j] = hp[j];
                bf16x8 bh, bl, bl2;
                split3x8(bv, bh, bl, bl2);
                mfma6(ah, al, al2, bh, bl, bl2, accM[jj], accC[jj]);
            }
        }
        __syncthreads();   // all waves done reading ht; I_l may overlay it

#pragma unroll
        for (int jj = 0; jj < 4; jj++) {
            const int job = wave + jj * 8;
            const int nt = job >> 1;
            const int n0 = nt * 16;
#pragma unroll
            for (int i = 0; i < 4; i++)
                I_l[(m0B + q * 4 + i) * 260 + n0 + r] = accM[jj][i] + accC[jj][i];
        }
    }
    __syncthreads();   // I complete; attn dead (shw may now overlay)

    // ================= phase C: w = cand @ I^T + parallel top-k (k5) =======
    {
        const float* Cb = cand + (size_t)b * NC * DD;
        const int job = wave;                    // 8 tiles, 1 per wave
        const int mt = job >> 1, nt = job & 1;
        const int m0 = mt * 16, n0 = nt * 16;
        f32x4 accM = zero, accC = zero;
#pragma unroll
        for (int ks = 0; ks < 8; ks++) {
            const float* ap = Cb + (size_t)(m0 + r) * DD + ks * 32 + q * 8;
            const float* bp = I_l + (n0 + r) * 260 + ks * 32 + q * 8;
            float4 u1 = *(const float4*)ap;      float4 u2 = *(const float4*)(ap + 4);
            float4 v1 = *(const float4*)bp;      float4 v2 = *(const float4*)(bp + 4);
            float av[8] = {u1.x,u1.y,u1.z,u1.w,u2.x,u2.y,u2.z,u2.w};
            float bv[8] = {v1.x,v1.y,v1.z,v1.w,v2.x,v2.y,v2.z,v2.w};
            bf16x8 ah, al, al2, bh, bl, bl2;
            split3x8(av, ah, al, al2);
            split3x8(bv, bh, bl, bl2);
            mfma6(ah, al, al2, bh, bl, bl2, accM, accC);
        }
#pragma unroll
        for (int i = 0; i < 4; i++) shw[(m0 + q * 4 + i) * 33 + n0 + r] = accM[i] + accC[i];

        __syncthreads();

        // parallel variable top-k: n = tid&63, k-group = tid>>6 (8 groups x 4)
        {
            const int n = tid & 63;
            const int kg = tid >> 6;             // 0..7
            int c8 = 8 * cc[b];
            int dynK = 32 - __clz(c8 - 1);
            dynK = min(max(dynK, 1), KK);
            float v[KK];
#pragma unroll
            for (int j = 0; j < KK; j++) v[j] = shw[n * 33 + j];
            float keep[4];
#pragma unroll
            for (int j = 0; j < 4; j++) {
                const int kk2 = kg + 8 * j;
                int rank = 0;
#pragma unroll
                for (int jj = 0; jj < KK; jj++)
                    rank += (v[jj] > v[kk2]) || (v[jj] == v[kk2] && jj < kk2);
                keep[j] = (rank < dynK) ? v[kk2] : 0.f;
            }
            __syncthreads();                     // all reads done before writes
#pragma unroll
            for (int j = 0; j < 4; j++)
                shw[n * 33 + kg + 8 * j] = keep[j];
        }
    }
    __syncthreads();   // masked w complete

    // ================= phase D: user = w_masked @ I (k6) ===================
    {
        const int d = tid & 255;
        const int nh = tid >> 8;
        float icol[KK];
#pragma unroll
        for (int k = 0; k < KK; k++) icol[k] = I_l[k * 260 + d];

        const int nend = nh * 32 + 32;
        for (int n = nh * 32; n < nend; n++) {
            const float* wr = shw + n * 33;
            float acc = 0.f;
#pragma unroll
            for (int k = 0; k < KK; k++) acc += wr[k] * icol[k];
            out[((size_t)b * NC + n) * DD + d] = acc;
        }
    }
}

// ---------------------------------------------------------------------------
extern "C" void kernel_launch(void* const* d_in, const int* in_sizes, int n_in,
                              void* d_out, int out_size, void* d_ws, size_t ws_size,
                              hipStream_t stream) {
    const float* hist = (const float*)d_in[0];
    const float* cand = (const float*)d_in[2];
    const int* ni = (const int*)d_in[3];
    const int* cc = (const int*)d_in[4];
    const float* W = (const float*)d_in[5];
    const float* C = (const float*)d_in[6];
    float* out = (float*)d_out;

    char* w8 = (char*)d_ws;
    float*  S   = (float*)(w8 + 0);
    bf16_t* Wh  = (bf16_t*)(w8 + OFF_WPL);
    bf16_t* Wl  = (bf16_t*)(w8 + OFF_WPL + 131072);
    bf16_t* Wl2 = (bf16_t*)(w8 + OFF_WPL + 262144);
    bf16_t* Ch  = (bf16_t*)(w8 + OFF_CPL);
    bf16_t* Cl  = (bf16_t*)(w8 + OFF_CPL + 16384);
    bf16_t* Cl2 = (bf16_t*)(w8 + OFF_CPL + 32768);

    kp_split<<<288, 256, 0, stream>>>(W, C, Wh, Wl, Wl2, Ch, Cl, Cl2);
    k12_proj_scores<<<BS, 448, 0, stream>>>(hist, Wh, Wl, Wl2, Ch, Cl, Cl2, S);
    k3456_fused<<<BS, 512, 0, stream>>>(S, ni, cc, hist, cand, out);
}